// Round 21
// baseline (30.973 us; speedup 1.0000x reference)
//
#include <hip/hip_runtime.h>

#define HH   48
#define WW   96
#define CC   256
#define DD   9
#define DD2  81
#define HWSZ (HH * WW)              // 4608
#define ROWB 512                    // bytes per bf16 channel row (256*2)
#define ZOFF ((unsigned)HWSZ * ROWB) // zero page offset from f2tb base
// pixel cells: 4 wide x 2 tall
#define NCX  24
#define NCY  24
#define NCELL (NCX * NCY)           // 576
#define HROWS 143                   // 11 x 13 halo rows
#define HRP   144                   // padded
#define HROWB 128                   // quarter-K halo row bytes (64 ch)
#define CAP  32                     // pixel list capacity (Poisson(8))
#define CBL_STR 104                 // cbl row stride in shorts (208 B, 16B-aligned)

typedef __attribute__((ext_vector_type(8))) short short8v;  // 8 bf16 (4 VGPRs)
typedef __attribute__((ext_vector_type(4))) float f32x4;

__device__ __forceinline__ unsigned bf16rne(float f) {      // RNE f32->bf16 bits
  unsigned u = __float_as_uint(f);
  return (u + 0x7FFFu + ((u >> 16) & 1u)) >> 16;
}

__device__ __forceinline__ void gload_lds16(const char* g, char* l) {
  __builtin_amdgcn_global_load_lds(
      (const __attribute__((address_space(1))) char*)g,
      (__attribute__((address_space(3))) char*)l, 16, 0, 0);
}

// ---------------- kernel 1: transposes + W-prep + pixel bucketing ----------------
// Vectorized: float4 global reads (1KB/wave-instr), b128 LDS writes (stride 68
// f32 = 272B, 16B-aligned), 2x16B stores per thread.
__global__ __launch_bounds__(256) void transpose_to_bf16(
    const float* __restrict__ f1, const float* __restrict__ f2,
    const float* __restrict__ w_dap, const float* __restrict__ coords,
    char* __restrict__ f2tb, char* __restrict__ f1tb, char* __restrict__ zpage,
    unsigned short* __restrict__ Wf, int* __restrict__ cnt,
    int* __restrict__ plist) {
  __shared__ __align__(16) float tile[64][68];      // 17408 B
  const float* src = (blockIdx.y == 0) ? f1 : f2;
  char* dst = (blockIdx.y == 0) ? f1tb : f2tb;

  const int tid = threadIdx.x;
  if (blockIdx.y == 0 && blockIdx.x == 0 && tid < 32) {   // zero the 512 B zero page
    float4 z = {0.f, 0.f, 0.f, 0.f};
    *(float4*)(zpage + tid * 16) = z;
  }
  if (blockIdx.y == 0 && blockIdx.x < 36) {   // W-prep: 9216 shorts over 36 blocks
    int gid = blockIdx.x * 256 + tid;
    int g = gid >> 9;                         // (m,kt) group 0..17
    int idx = gid & 511;
    int ln = idx >> 3, e = idx & 7;
    int m = g / 3, kt = g - m * 3;
    int r = m * 16 + (ln & 15);
    int c = kt * 32 + (ln >> 4) * 8 + e;
    float v = (r < DD2 && c < DD2) ? w_dap[r * DD2 + c] : 0.f;
    Wf[gid] = (unsigned short)bf16rne(v);
  }
  if (blockIdx.y == 1 && blockIdx.x < 18) {   // bucket pixels (cnt pre-zeroed)
    const int p = blockIdx.x * 256 + tid;
    const int ix = (int)coords[p];
    const int iy = (int)coords[HWSZ + p];
    const int cell = (iy >> 1) * NCX + (ix >> 2);
    const int slot = atomicAdd(&cnt[cell], 1);
    if (slot < CAP) plist[cell * CAP + slot] = p;
  }

  const int tiles_p = HWSZ / 64;              // 72
  const int bc = blockIdx.x / tiles_p;        // channel tile 0..3
  const int bp = blockIdx.x % tiles_p;        // pixel tile 0..71
  const int c0 = bc * 64, p0 = bp * 64;

#pragma unroll
  for (int k = 0; k < 4; k++) {               // 1024 float4 reads, coalesced
    int idx = k * 256 + tid;
    int cl = idx >> 4, q = idx & 15;          // 16 float4 per 64-px row
    float4 v = *(const float4*)(src + (size_t)(c0 + cl) * HWSZ + p0 + q * 4);
    *(float4*)&tile[cl][q * 4] = v;           // b128 LDS write, 2-way banks
  }
  __syncthreads();
  {
    const int px = tid >> 2, part = tid & 3;  // thread -> pixel, 16-ch slice
    unsigned w[8];
#pragma unroll
    for (int j = 0; j < 8; j++) {
      unsigned lo = bf16rne(tile[part * 16 + 2 * j][px]);
      unsigned hi = bf16rne(tile[part * 16 + 2 * j + 1][px]);
      w[j] = lo | (hi << 16);
    }
    char* dp = dst + (size_t)(p0 + px) * ROWB + c0 * 2 + part * 32;
    float4 v0 = {__uint_as_float(w[0]), __uint_as_float(w[1]),
                 __uint_as_float(w[2]), __uint_as_float(w[3])};
    float4 v1 = {__uint_as_float(w[4]), __uint_as_float(w[5]),
                 __uint_as_float(w[6]), __uint_as_float(w[7])};
    *(float4*)dp = v0;
    *(float4*)(dp + 16) = v1;
  }
}

// ---------------- kernel 2: per-cell halo GEMM (4-pass K-split) + bilinear + DAP ----------------
// LDS 31.6KB -> 5 blocks/CU (was 49.5KB/3): barrier + L2-latency exposure now
// overlaps across ~20 waves/SIMD. Same staging bytes/instrs, same 72 MFMAs.
__global__ __launch_bounds__(256, 4) void corr_region(
    const char* __restrict__ f2tb, const char* __restrict__ f1tb,
    const float* __restrict__ coords, const int* __restrict__ cnt,
    const int* __restrict__ plist, const unsigned short* __restrict__ Wf,
    float* __restrict__ out) {
  __shared__ __align__(16) char halo[HRP * HROWB];  // 18432 B
  __shared__ float dsf[HRP * 16];                   // 9216 B
  __shared__ unsigned rowoff[HRP];                  // 576 B
  __shared__ __align__(16) unsigned short cbl[16 * CBL_STR];  // 3328 B

  const int cell = blockIdx.x;
  const int ci = cell % NCX, cj = cell / NCX;
  const int npix0 = cnt[cell];
  const int npix = npix0 < CAP ? npix0 : CAP;
  if (npix == 0) return;

  const int tid = threadIdx.x;
  const int lane = tid & 63, wid = tid >> 6;
  const int hi = lane >> 4, lo = lane & 15;

  const int hx0 = ci * 4 - 4, hy0 = cj * 2 - 4;     // halo origin

  if (tid < HRP) {                            // r -> f2tb byte offset (pad -> zero page)
    unsigned ro = ZOFF;
    if (tid < HROWS) {
      const int hy = (tid * 158) >> 11;       // r/13 (exact for r<143)
      const int hx = tid - hy * 13;
      const int gy = hy0 + hy, gx = hx0 + hx;
      if (gx >= 0 && gx < WW && gy >= 0 && gy < HH)
        ro = (unsigned)(gy * WW + gx) * ROWB;
    }
    rowoff[tid] = ro;
  }
  __syncthreads();

  // staging address components (constant per lane; r&7 == lane>>3)
  const int srow = lane >> 3;                 // row within 8-row instr group
  const int sOff = ((lane & 7) * 16) ^ (srow << 4);  // pre-swizzled byte col

  const int nb = (npix + 15) >> 4;
  for (int b = 0; b < nb; ++b) {
    // B fragments: 16 pixel columns (col = lo); invalid slots -> zero page
    const int slot = b * 16 + lo;
    const bool valid = slot < npix;
    const int pi = valid ? plist[cell * CAP + slot] : 0;
    const char* fb = valid ? (f1tb + (size_t)pi * ROWB) : (f2tb + ZOFF);
    short8v bq[8];
#pragma unroll
    for (int kt = 0; kt < 8; kt++)
      bq[kt] = *(const short8v*)(fb + kt * 64 + hi * 16);

    // tile ownership: t0 = wid, t1 = wid+4, t2 = 8 (wid 0 only); 9 tiles x 16 rows
    f32x4 acc0 = {0.f, 0.f, 0.f, 0.f};
    f32x4 acc1 = {0.f, 0.f, 0.f, 0.f};
    f32x4 acc2 = {0.f, 0.f, 0.f, 0.f};

#pragma unroll
    for (int pass = 0; pass < 4; pass++) {    // 64 channels per pass
      // stage 144 rows x 128B; 8 rows/instr; source pre-swizzled (dest linear)
      for (int s = wid; s < 18; s += 4) {
        const int r = 8 * s + srow;
        gload_lds16(f2tb + rowoff[r] + pass * 128 + sOff, &halo[s * 1024]);
      }
      __syncthreads();                        // staging done (vmcnt drained)

      {
        const int rr = wid * 16 + lo;
        const int swz = (rr & 7) << 4;
        const char* rp = halo + rr * HROWB;
        short8v a0 = *(const short8v*)(rp + ((hi * 16) ^ swz));
        short8v a1 = *(const short8v*)(rp + ((hi * 16 + 64) ^ swz));
        acc0 = __builtin_amdgcn_mfma_f32_16x16x32_bf16(a0, bq[pass * 2 + 0], acc0, 0, 0, 0);
        acc0 = __builtin_amdgcn_mfma_f32_16x16x32_bf16(a1, bq[pass * 2 + 1], acc0, 0, 0, 0);
      }
      {
        const int rr = (wid + 4) * 16 + lo;
        const int swz = (rr & 7) << 4;
        const char* rp = halo + rr * HROWB;
        short8v a0 = *(const short8v*)(rp + ((hi * 16) ^ swz));
        short8v a1 = *(const short8v*)(rp + ((hi * 16 + 64) ^ swz));
        acc1 = __builtin_amdgcn_mfma_f32_16x16x32_bf16(a0, bq[pass * 2 + 0], acc1, 0, 0, 0);
        acc1 = __builtin_amdgcn_mfma_f32_16x16x32_bf16(a1, bq[pass * 2 + 1], acc1, 0, 0, 0);
      }
      if (wid == 0) {
        const int rr = 8 * 16 + lo;
        const int swz = (rr & 7) << 4;
        const char* rp = halo + rr * HROWB;
        short8v a0 = *(const short8v*)(rp + ((hi * 16) ^ swz));
        short8v a1 = *(const short8v*)(rp + ((hi * 16 + 64) ^ swz));
        acc2 = __builtin_amdgcn_mfma_f32_16x16x32_bf16(a0, bq[pass * 2 + 0], acc2, 0, 0, 0);
        acc2 = __builtin_amdgcn_mfma_f32_16x16x32_bf16(a1, bq[pass * 2 + 1], acc2, 0, 0, 0);
      }
      __syncthreads();                        // reads done before restage
    }

    // D layout: col = lo, row = hi*4 + j
#pragma unroll
    for (int j = 0; j < 4; j++)
      dsf[(wid * 16 + hi * 4 + j) * 16 + lo] = acc0[j];
#pragma unroll
    for (int j = 0; j < 4; j++)
      dsf[((wid + 4) * 16 + hi * 4 + j) * 16 + lo] = acc1[j];
    if (wid == 0) {
#pragma unroll
      for (int j = 0; j < 4; j++)
        dsf[(8 * 16 + hi * 4 + j) * 16 + lo] = acc2[j];
    }
    __syncthreads();                          // dsf ready

    // bilinear: thread t -> pixel slot t&15, outputs o in [(t>>4)*6, +6)
    // writes ALL 96 k-rows of cbl (zeros for o>=81)
    {
      const int s2 = tid & 15;
      const int g = tid >> 4;
      const int slot2 = b * 16 + s2;
      if (slot2 < npix) {
        const int pi2 = plist[cell * CAP + slot2];
        const float cx = coords[pi2];
        const float cy = coords[HWSZ + pi2];
        const float fxf = floorf(cx), fyf = floorf(cy);
        const float fx = cx - fxf, fy = cy - fyf;
        const int ox = (int)fxf - ci * 4;     // 0..3
        const int oy = (int)fyf - cj * 2;     // 0..1
#pragma unroll
        for (int e = 0; e < 6; e++) {
          const int o = g * 6 + e;
          float cv = 0.f;
          if (o < DD2) {
            const int i = o / DD, j = o - i * DD;   // i=x-offset, j=y-offset
            const int rb = (oy + j) * 13 + ox + i;  // <= 128
            const float d00 = dsf[rb * 16 + s2];
            const float d01 = dsf[(rb + 1) * 16 + s2];
            const float d10 = dsf[(rb + 13) * 16 + s2];
            const float d11 = dsf[(rb + 14) * 16 + s2];
            cv = ((1.f - fy) * ((1.f - fx) * d00 + fx * d01) +
                  fy * ((1.f - fx) * d10 + fx * d11)) * 0.0625f;
          }
          cbl[s2 * CBL_STR + o] = (unsigned short)bf16rne(cv);
        }
      }
    }
    __syncthreads();                          // cbl ready

    // ---- fused DAP: out[o][px] = W(96x96).cbl ; A = Wf fragment-major ----
    {
      short8v bq2[3];
#pragma unroll
      for (int kt = 0; kt < 3; kt++)
        bq2[kt] = *(const short8v*)&cbl[lo * CBL_STR + kt * 32 + hi * 8];
      const int slot3 = b * 16 + lo;
      const bool v3 = slot3 < npix;
      const int po = v3 ? plist[cell * CAP + slot3] : 0;
#pragma unroll
      for (int mi = 0; mi < 2; mi++) {
        const int m = wid + mi * 4;
        if (m < 6) {
          f32x4 acc = {0.f, 0.f, 0.f, 0.f};
#pragma unroll
          for (int kt = 0; kt < 3; kt++) {
            short8v aw = *(const short8v*)(Wf + ((size_t)(m * 3 + kt) * 64 + lane) * 8);
            acc = __builtin_amdgcn_mfma_f32_16x16x32_bf16(aw, bq2[kt], acc, 0, 0, 0);
          }
          if (v3) {
#pragma unroll
            for (int j = 0; j < 4; j++) {
              const int o = m * 16 + hi * 4 + j;
              if (o < DD2) out[(size_t)o * HWSZ + po] = acc[j];
            }
          }
        }
      }
    }
    if (b + 1 < nb) __syncthreads();          // protect dsf/halo/cbl before next batch
  }
}

extern "C" void kernel_launch(void* const* d_in, const int* in_sizes, int n_in,
                              void* d_out, int out_size, void* d_ws, size_t ws_size,
                              hipStream_t stream) {
  const float* f1     = (const float*)d_in[0];
  const float* f2     = (const float*)d_in[1];
  const float* coords = (const float*)d_in[2];
  const float* w_dap  = (const float*)d_in[3];
  float* out = (float*)d_out;

  // ws: [f2tb 2359296][zpage 512][f1tb 2359296][Wf 18432][cnt 2304][plist 73728]
  char* f2tb  = (char*)d_ws;
  char* zpage = f2tb + (size_t)HWSZ * ROWB;
  char* f1tb  = zpage + 512;
  unsigned short* Wf = (unsigned short*)(f1tb + (size_t)HWSZ * ROWB);
  int* cnt   = (int*)(Wf + 9216);
  int* plist = cnt + NCELL;

  hipMemsetAsync(cnt, 0, NCELL * sizeof(int), stream);

  dim3 tgrid((CC / 64) * (HWSZ / 64), 2);
  transpose_to_bf16<<<tgrid, 256, 0, stream>>>(f1, f2, w_dap, coords, f2tb, f1tb,
                                               zpage, Wf, cnt, plist);

  corr_region<<<dim3(NCELL), 256, 0, stream>>>(f2tb, f1tb, coords, cnt, plist, Wf, out);
}

// Round 22
// 30.233 us; speedup vs baseline: 1.0245x; 1.0245x over previous
//
#include <hip/hip_runtime.h>

#define HH   48
#define WW   96
#define CC   256
#define DD   9
#define DD2  81
#define HWSZ (HH * WW)              // 4608
#define ROWB 512                    // bytes per bf16 channel row (256*2)
#define ZOFF ((unsigned)HWSZ * ROWB) // zero page offset from f2tb base
// pixel cells: 4 wide x 2 tall
#define NCX  24
#define NCY  24
#define NCELL (NCX * NCY)           // 576
#define HROWS 143                   // 11 x 13 halo rows
#define HRP   144                   // padded
#define HROWB 256                   // half-K halo row bytes (128 ch)
#define CAP  32                     // pixel list capacity (Poisson(8))
#define CBL_STR 104                 // cbl row stride in shorts (208 B, 16B-aligned)

typedef __attribute__((ext_vector_type(8))) short short8v;  // 8 bf16 (4 VGPRs)
typedef __attribute__((ext_vector_type(4))) float f32x4;

__device__ __forceinline__ unsigned bf16rne(float f) {      // RNE f32->bf16 bits
  unsigned u = __float_as_uint(f);
  return (u + 0x7FFFu + ((u >> 16) & 1u)) >> 16;
}

__device__ __forceinline__ void gload_lds16(const char* g, char* l) {
  __builtin_amdgcn_global_load_lds(
      (const __attribute__((address_space(1))) char*)g,
      (__attribute__((address_space(3))) char*)l, 16, 0, 0);
}

// ---------------- kernel 1: transposes + W-prep + pixel bucketing (vectorized) ----------------
// float4 global reads (1KB/wave-instr), b128 LDS writes (stride 68 f32 = 272B,
// 16B-aligned), 2x16B stores per thread.
__global__ __launch_bounds__(256) void transpose_to_bf16(
    const float* __restrict__ f1, const float* __restrict__ f2,
    const float* __restrict__ w_dap, const float* __restrict__ coords,
    char* __restrict__ f2tb, char* __restrict__ f1tb, char* __restrict__ zpage,
    unsigned short* __restrict__ Wf, int* __restrict__ cnt,
    int* __restrict__ plist) {
  __shared__ __align__(16) float tile[64][68];      // 17408 B
  const float* src = (blockIdx.y == 0) ? f1 : f2;
  char* dst = (blockIdx.y == 0) ? f1tb : f2tb;

  const int tid = threadIdx.x;
  if (blockIdx.y == 0 && blockIdx.x == 0 && tid < 32) {   // zero the 512 B zero page
    float4 z = {0.f, 0.f, 0.f, 0.f};
    *(float4*)(zpage + tid * 16) = z;
  }
  if (blockIdx.y == 0 && blockIdx.x < 36) {   // W-prep: 9216 shorts over 36 blocks
    int gid = blockIdx.x * 256 + tid;
    int g = gid >> 9;                         // (m,kt) group 0..17
    int idx = gid & 511;
    int ln = idx >> 3, e = idx & 7;
    int m = g / 3, kt = g - m * 3;
    int r = m * 16 + (ln & 15);
    int c = kt * 32 + (ln >> 4) * 8 + e;
    float v = (r < DD2 && c < DD2) ? w_dap[r * DD2 + c] : 0.f;
    Wf[gid] = (unsigned short)bf16rne(v);
  }
  if (blockIdx.y == 1 && blockIdx.x < 18) {   // bucket pixels (cnt pre-zeroed)
    const int p = blockIdx.x * 256 + tid;
    const int ix = (int)coords[p];
    const int iy = (int)coords[HWSZ + p];
    const int cell = (iy >> 1) * NCX + (ix >> 2);
    const int slot = atomicAdd(&cnt[cell], 1);
    if (slot < CAP) plist[cell * CAP + slot] = p;
  }

  const int tiles_p = HWSZ / 64;              // 72
  const int bc = blockIdx.x / tiles_p;        // channel tile 0..3
  const int bp = blockIdx.x % tiles_p;        // pixel tile 0..71
  const int c0 = bc * 64, p0 = bp * 64;

#pragma unroll
  for (int k = 0; k < 4; k++) {               // 1024 float4 reads, coalesced
    int idx = k * 256 + tid;
    int cl = idx >> 4, q = idx & 15;          // 16 float4 per 64-px row
    float4 v = *(const float4*)(src + (size_t)(c0 + cl) * HWSZ + p0 + q * 4);
    *(float4*)&tile[cl][q * 4] = v;           // b128 LDS write, 2-way banks
  }
  __syncthreads();
  {
    const int px = tid >> 2, part = tid & 3;  // thread -> pixel, 16-ch slice
    unsigned w[8];
#pragma unroll
    for (int j = 0; j < 8; j++) {
      unsigned lo = bf16rne(tile[part * 16 + 2 * j][px]);
      unsigned hi = bf16rne(tile[part * 16 + 2 * j + 1][px]);
      w[j] = lo | (hi << 16);
    }
    char* dp = dst + (size_t)(p0 + px) * ROWB + c0 * 2 + part * 32;
    float4 v0 = {__uint_as_float(w[0]), __uint_as_float(w[1]),
                 __uint_as_float(w[2]), __uint_as_float(w[3])};
    float4 v1 = {__uint_as_float(w[4]), __uint_as_float(w[5]),
                 __uint_as_float(w[6]), __uint_as_float(w[7])};
    *(float4*)dp = v0;
    *(float4*)(dp + 16) = v1;
  }
}

// ---------------- kernel 2: per-cell halo GEMM (2-pass K-split) + bilinear + DAP ----------------
// R20 champion config: LDS 49.5KB -> 3 blocks/CU, 4 barriers/batch.
// (R21's 4-pass split regressed: 8 barriers/batch cost > occupancy gain.)
__global__ __launch_bounds__(256, 3) void corr_region(
    const char* __restrict__ f2tb, const char* __restrict__ f1tb,
    const float* __restrict__ coords, const int* __restrict__ cnt,
    const int* __restrict__ plist, const unsigned short* __restrict__ Wf,
    float* __restrict__ out) {
  __shared__ __align__(16) char halo[HRP * HROWB];  // 36864 B
  __shared__ float dsf[HRP * 16];                   // 9216 B
  __shared__ unsigned rowoff[HRP];                  // 576 B
  __shared__ __align__(16) unsigned short cbl[16 * CBL_STR];  // 3328 B

  const int cell = blockIdx.x;
  const int ci = cell % NCX, cj = cell / NCX;
  const int npix0 = cnt[cell];
  const int npix = npix0 < CAP ? npix0 : CAP;
  if (npix == 0) return;

  const int tid = threadIdx.x;
  const int lane = tid & 63, wid = tid >> 6;
  const int hi = lane >> 4, lo = lane & 15;

  const int hx0 = ci * 4 - 4, hy0 = cj * 2 - 4;     // halo origin

  if (tid < HRP) {                            // r -> f2tb byte offset (pad -> zero page)
    unsigned ro = ZOFF;
    if (tid < HROWS) {
      const int hy = (tid * 158) >> 11;       // r/13 (exact for r<143)
      const int hx = tid - hy * 13;
      const int gy = hy0 + hy, gx = hx0 + hx;
      if (gx >= 0 && gx < WW && gy >= 0 && gy < HH)
        ro = (unsigned)(gy * WW + gx) * ROWB;
    }
    rowoff[tid] = ro;
  }
  __syncthreads();

  const int nb = (npix + 15) >> 4;
  for (int b = 0; b < nb; ++b) {
    // B fragments: 16 pixel columns (col = lo); invalid slots -> zero page
    const int slot = b * 16 + lo;
    const bool valid = slot < npix;
    const int pi = valid ? plist[cell * CAP + slot] : 0;
    const char* fb = valid ? (f1tb + (size_t)pi * ROWB) : (f2tb + ZOFF);
    short8v bq[8];
#pragma unroll
    for (int kt = 0; kt < 8; kt++)
      bq[kt] = *(const short8v*)(fb + kt * 64 + hi * 16);

    // tile ownership: t0 = wid, t1 = wid+4, t2 = 8 (wid 0 only); 9 tiles of 16 rows
    f32x4 acc0 = {0.f, 0.f, 0.f, 0.f};
    f32x4 acc1 = {0.f, 0.f, 0.f, 0.f};
    f32x4 acc2 = {0.f, 0.f, 0.f, 0.f};

#pragma unroll
    for (int pass = 0; pass < 2; pass++) {
      // stage 144 rows x 256B; 4 rows/instr; source pre-swizzled (dest linear)
      for (int s = wid; s < 36; s += 4) {
        const int r = 4 * s + hi;
        gload_lds16(
            f2tb + rowoff[r] + pass * 256 + ((lo * 16) ^ ((r & 7) << 4)),
            &halo[s * 1024]);
      }
      __syncthreads();                        // staging done (vmcnt drained)

      {
        const int rr = wid * 16 + lo;
        const int swz = (rr & 7) << 4;
        const char* rp = halo + rr * HROWB;
        short8v a0 = *(const short8v*)(rp + ((hi * 16 + 0) ^ swz));
        short8v a1 = *(const short8v*)(rp + ((hi * 16 + 64) ^ swz));
        short8v a2 = *(const short8v*)(rp + ((hi * 16 + 128) ^ swz));
        short8v a3 = *(const short8v*)(rp + ((hi * 16 + 192) ^ swz));
        acc0 = __builtin_amdgcn_mfma_f32_16x16x32_bf16(a0, bq[pass * 4 + 0], acc0, 0, 0, 0);
        acc0 = __builtin_amdgcn_mfma_f32_16x16x32_bf16(a1, bq[pass * 4 + 1], acc0, 0, 0, 0);
        acc0 = __builtin_amdgcn_mfma_f32_16x16x32_bf16(a2, bq[pass * 4 + 2], acc0, 0, 0, 0);
        acc0 = __builtin_amdgcn_mfma_f32_16x16x32_bf16(a3, bq[pass * 4 + 3], acc0, 0, 0, 0);
      }
      {
        const int rr = (wid + 4) * 16 + lo;
        const int swz = (rr & 7) << 4;
        const char* rp = halo + rr * HROWB;
        short8v a0 = *(const short8v*)(rp + ((hi * 16 + 0) ^ swz));
        short8v a1 = *(const short8v*)(rp + ((hi * 16 + 64) ^ swz));
        short8v a2 = *(const short8v*)(rp + ((hi * 16 + 128) ^ swz));
        short8v a3 = *(const short8v*)(rp + ((hi * 16 + 192) ^ swz));
        acc1 = __builtin_amdgcn_mfma_f32_16x16x32_bf16(a0, bq[pass * 4 + 0], acc1, 0, 0, 0);
        acc1 = __builtin_amdgcn_mfma_f32_16x16x32_bf16(a1, bq[pass * 4 + 1], acc1, 0, 0, 0);
        acc1 = __builtin_amdgcn_mfma_f32_16x16x32_bf16(a2, bq[pass * 4 + 2], acc1, 0, 0, 0);
        acc1 = __builtin_amdgcn_mfma_f32_16x16x32_bf16(a3, bq[pass * 4 + 3], acc1, 0, 0, 0);
      }
      if (wid == 0) {
        const int rr = 8 * 16 + lo;
        const int swz = (rr & 7) << 4;
        const char* rp = halo + rr * HROWB;
        short8v a0 = *(const short8v*)(rp + ((hi * 16 + 0) ^ swz));
        short8v a1 = *(const short8v*)(rp + ((hi * 16 + 64) ^ swz));
        short8v a2 = *(const short8v*)(rp + ((hi * 16 + 128) ^ swz));
        short8v a3 = *(const short8v*)(rp + ((hi * 16 + 192) ^ swz));
        acc2 = __builtin_amdgcn_mfma_f32_16x16x32_bf16(a0, bq[pass * 4 + 0], acc2, 0, 0, 0);
        acc2 = __builtin_amdgcn_mfma_f32_16x16x32_bf16(a1, bq[pass * 4 + 1], acc2, 0, 0, 0);
        acc2 = __builtin_amdgcn_mfma_f32_16x16x32_bf16(a2, bq[pass * 4 + 2], acc2, 0, 0, 0);
        acc2 = __builtin_amdgcn_mfma_f32_16x16x32_bf16(a3, bq[pass * 4 + 3], acc2, 0, 0, 0);
      }
      __syncthreads();                        // reads done before restage/overwrite
    }

    // D layout: col = lo, row = hi*4 + j
#pragma unroll
    for (int j = 0; j < 4; j++)
      dsf[(wid * 16 + hi * 4 + j) * 16 + lo] = acc0[j];
#pragma unroll
    for (int j = 0; j < 4; j++)
      dsf[((wid + 4) * 16 + hi * 4 + j) * 16 + lo] = acc1[j];
    if (wid == 0) {
#pragma unroll
      for (int j = 0; j < 4; j++)
        dsf[(8 * 16 + hi * 4 + j) * 16 + lo] = acc2[j];
    }
    __syncthreads();                          // dsf ready

    // bilinear: thread t -> pixel slot t&15, outputs o in [(t>>4)*6, +6)
    // writes ALL 96 k-rows of cbl (zeros for o>=81)
    {
      const int s2 = tid & 15;
      const int g = tid >> 4;
      const int slot2 = b * 16 + s2;
      if (slot2 < npix) {
        const int pi2 = plist[cell * CAP + slot2];
        const float cx = coords[pi2];
        const float cy = coords[HWSZ + pi2];
        const float fxf = floorf(cx), fyf = floorf(cy);
        const float fx = cx - fxf, fy = cy - fyf;
        const int ox = (int)fxf - ci * 4;     // 0..3
        const int oy = (int)fyf - cj * 2;     // 0..1
#pragma unroll
        for (int e = 0; e < 6; e++) {
          const int o = g * 6 + e;
          float cv = 0.f;
          if (o < DD2) {
            const int i = o / DD, j = o - i * DD;   // i=x-offset, j=y-offset
            const int rb = (oy + j) * 13 + ox + i;  // <= 128
            const float d00 = dsf[rb * 16 + s2];
            const float d01 = dsf[(rb + 1) * 16 + s2];
            const float d10 = dsf[(rb + 13) * 16 + s2];
            const float d11 = dsf[(rb + 14) * 16 + s2];
            cv = ((1.f - fy) * ((1.f - fx) * d00 + fx * d01) +
                  fy * ((1.f - fx) * d10 + fx * d11)) * 0.0625f;
          }
          cbl[s2 * CBL_STR + o] = (unsigned short)bf16rne(cv);
        }
      }
    }
    __syncthreads();                          // cbl ready

    // ---- fused DAP: out[o][px] = W(96x96).cbl ; A = Wf fragment-major ----
    {
      short8v bq2[3];
#pragma unroll
      for (int kt = 0; kt < 3; kt++)
        bq2[kt] = *(const short8v*)&cbl[lo * CBL_STR + kt * 32 + hi * 8];
      const int slot3 = b * 16 + lo;
      const bool v3 = slot3 < npix;
      const int po = v3 ? plist[cell * CAP + slot3] : 0;
#pragma unroll
      for (int mi = 0; mi < 2; mi++) {
        const int m = wid + mi * 4;
        if (m < 6) {
          f32x4 acc = {0.f, 0.f, 0.f, 0.f};
#pragma unroll
          for (int kt = 0; kt < 3; kt++) {
            short8v aw = *(const short8v*)(Wf + ((size_t)(m * 3 + kt) * 64 + lane) * 8);
            acc = __builtin_amdgcn_mfma_f32_16x16x32_bf16(aw, bq2[kt], acc, 0, 0, 0);
          }
          if (v3) {
#pragma unroll
            for (int j = 0; j < 4; j++) {
              const int o = m * 16 + hi * 4 + j;
              if (o < DD2) out[(size_t)o * HWSZ + po] = acc[j];
            }
          }
        }
      }
    }
    if (b + 1 < nb) __syncthreads();          // protect dsf/halo/cbl before next batch
  }
}

extern "C" void kernel_launch(void* const* d_in, const int* in_sizes, int n_in,
                              void* d_out, int out_size, void* d_ws, size_t ws_size,
                              hipStream_t stream) {
  const float* f1     = (const float*)d_in[0];
  const float* f2     = (const float*)d_in[1];
  const float* coords = (const float*)d_in[2];
  const float* w_dap  = (const float*)d_in[3];
  float* out = (float*)d_out;

  // ws: [f2tb 2359296][zpage 512][f1tb 2359296][Wf 18432][cnt 2304][plist 73728]
  char* f2tb  = (char*)d_ws;
  char* zpage = f2tb + (size_t)HWSZ * ROWB;
  char* f1tb  = zpage + 512;
  unsigned short* Wf = (unsigned short*)(f1tb + (size_t)HWSZ * ROWB);
  int* cnt   = (int*)(Wf + 9216);
  int* plist = cnt + NCELL;

  hipMemsetAsync(cnt, 0, NCELL * sizeof(int), stream);

  dim3 tgrid((CC / 64) * (HWSZ / 64), 2);
  transpose_to_bf16<<<tgrid, 256, 0, stream>>>(f1, f2, w_dap, coords, f2tb, f1tb,
                                               zpage, Wf, cnt, plist);

  corr_region<<<dim3(NCELL), 256, 0, stream>>>(f2tb, f1tb, coords, cnt, plist, Wf, out);
}

// Round 23
// 30.027 us; speedup vs baseline: 1.0315x; 1.0068x over previous
//
#include <hip/hip_runtime.h>

#define HH   48
#define WW   96
#define CC   256
#define DD   9
#define DD2  81
#define HWSZ (HH * WW)              // 4608
#define ROWB 512                    // bytes per bf16 channel row (256*2)
#define ZOFF ((unsigned)HWSZ * ROWB) // zero page offset from f2tb base
// pixel cells: 4 wide x 2 tall
#define NCX  24
#define NCY  24
#define NCELL (NCX * NCY)           // 576
#define HROWS 143                   // 11 x 13 halo rows
#define HRP   144                   // padded
#define HROWB 256                   // half-K halo row bytes (128 ch)
#define CAP  32                     // pixel list capacity (Poisson(8))
#define CBL_STR 104                 // cbl row stride in shorts (208 B, 16B-aligned)

typedef __attribute__((ext_vector_type(8))) short short8v;  // 8 bf16 (4 VGPRs)
typedef __attribute__((ext_vector_type(4))) float f32x4;

__device__ __forceinline__ unsigned bf16rne(float f) {      // RNE f32->bf16 bits
  unsigned u = __float_as_uint(f);
  return (u + 0x7FFFu + ((u >> 16) & 1u)) >> 16;
}

__device__ __forceinline__ void gload_lds16(const char* g, char* l) {
  __builtin_amdgcn_global_load_lds(
      (const __attribute__((address_space(1))) char*)g,
      (__attribute__((address_space(3))) char*)l, 16, 0, 0);
}

// ---------------- kernel 1: transposes + W-prep + pixel bucketing (R20 version) ----------------
__global__ __launch_bounds__(256) void transpose_to_bf16(
    const float* __restrict__ f1, const float* __restrict__ f2,
    const float* __restrict__ w_dap, const float* __restrict__ coords,
    char* __restrict__ f2tb, char* __restrict__ f1tb, char* __restrict__ zpage,
    unsigned short* __restrict__ Wf, int* __restrict__ cnt,
    int* __restrict__ plist) {
  __shared__ float tile[64][65];
  const float* src = (blockIdx.y == 0) ? f1 : f2;
  char* dst = (blockIdx.y == 0) ? f1tb : f2tb;

  const int tid = threadIdx.x;
  if (blockIdx.y == 0 && blockIdx.x == 0 && tid < 32) {   // zero the 512 B zero page
    float4 z = {0.f, 0.f, 0.f, 0.f};
    *(float4*)(zpage + tid * 16) = z;
  }
  if (blockIdx.y == 0 && blockIdx.x < 36) {   // W-prep: 9216 shorts over 36 blocks
    int gid = blockIdx.x * 256 + tid;
    int g = gid >> 9;                         // (m,kt) group 0..17
    int idx = gid & 511;
    int ln = idx >> 3, e = idx & 7;
    int m = g / 3, kt = g - m * 3;
    int r = m * 16 + (ln & 15);
    int c = kt * 32 + (ln >> 4) * 8 + e;
    float v = (r < DD2 && c < DD2) ? w_dap[r * DD2 + c] : 0.f;
    Wf[gid] = (unsigned short)bf16rne(v);
  }
  if (blockIdx.y == 1 && blockIdx.x < 18) {   // bucket pixels (cnt pre-zeroed)
    const int p = blockIdx.x * 256 + tid;
    const int ix = (int)coords[p];
    const int iy = (int)coords[HWSZ + p];
    const int cell = (iy >> 1) * NCX + (ix >> 2);
    const int slot = atomicAdd(&cnt[cell], 1);
    if (slot < CAP) plist[cell * CAP + slot] = p;
  }

  const int tiles_p = HWSZ / 64;              // 72
  const int bc = blockIdx.x / tiles_p;        // channel tile 0..3
  const int bp = blockIdx.x % tiles_p;        // pixel tile 0..71
  const int c0 = bc * 64, p0 = bp * 64;

#pragma unroll
  for (int k = 0; k < 16; k++) {
    int idx = k * 256 + tid;
    int cl = idx >> 6, pl = idx & 63;         // coalesced over pixels
    tile[cl][pl] = src[(size_t)(c0 + cl) * HWSZ + p0 + pl];
  }
  __syncthreads();
#pragma unroll
  for (int k = 0; k < 8; k++) {               // pack 2 channels -> 4 B stores
    int idx = k * 256 + tid;
    int pl = idx >> 5, cp = idx & 31;
    unsigned lo = bf16rne(tile[2 * cp][pl]);
    unsigned hi = bf16rne(tile[2 * cp + 1][pl]);
    *(unsigned*)(dst + (size_t)(p0 + pl) * ROWB + (size_t)c0 * 2 + cp * 4) =
        lo | (hi << 16);
  }
}

// ---------------- kernel 2: per-cell halo GEMM, WAVE-OWNED staging ----------------
// Wave w stages exactly the halo rows of its own tiles {w, w+4} (+ tile 8 for
// w0): staging<->MFMA sync is per-wave vmcnt(0)+sched_barrier, not block
// barriers. lgkmcnt(0) fence before pass-1 restage (ds_reads sampled before
// DMA lands). Block barriers: 2/batch (dsf-ready, cbl-ready) vs R20's 6.
__global__ __launch_bounds__(256, 3) void corr_region(
    const char* __restrict__ f2tb, const char* __restrict__ f1tb,
    const float* __restrict__ coords, const int* __restrict__ cnt,
    const int* __restrict__ plist, const unsigned short* __restrict__ Wf,
    float* __restrict__ out) {
  __shared__ __align__(16) char halo[HRP * HROWB];  // 36864 B
  __shared__ float dsf[HRP * 16];                   // 9216 B
  __shared__ unsigned rowoff[HRP];                  // 576 B
  __shared__ __align__(16) unsigned short cbl[16 * CBL_STR];  // 3328 B

  const int cell = blockIdx.x;
  const int ci = cell % NCX, cj = cell / NCX;
  const int npix0 = cnt[cell];
  const int npix = npix0 < CAP ? npix0 : CAP;
  if (npix == 0) return;

  const int tid = threadIdx.x;
  const int lane = tid & 63, wid = tid >> 6;
  const int hi = lane >> 4, lo = lane & 15;

  const int hx0 = ci * 4 - 4, hy0 = cj * 2 - 4;     // halo origin

  if (tid < HRP) {                            // r -> f2tb byte offset (pad -> zero page)
    unsigned ro = ZOFF;
    if (tid < HROWS) {
      const int hy = (tid * 158) >> 11;       // r/13 (exact for r<143)
      const int hx = tid - hy * 13;
      const int gy = hy0 + hy, gx = hx0 + hx;
      if (gx >= 0 && gx < WW && gy >= 0 && gy < HH)
        ro = (unsigned)(gy * WW + gx) * ROWB;
    }
    rowoff[tid] = ro;
  }
  __syncthreads();                            // rowoff ready (once per block)

  const int nb = (npix + 15) >> 4;
  for (int b = 0; b < nb; ++b) {
    // B fragments: 16 pixel columns (col = lo); invalid slots -> zero page
    const int slot = b * 16 + lo;
    const bool valid = slot < npix;
    const int pi = valid ? plist[cell * CAP + slot] : 0;
    const char* fb = valid ? (f1tb + (size_t)pi * ROWB) : (f2tb + ZOFF);
    short8v bq[8];
#pragma unroll
    for (int kt = 0; kt < 8; kt++)
      bq[kt] = *(const short8v*)(fb + kt * 64 + hi * 16);

    f32x4 acc0 = {0.f, 0.f, 0.f, 0.f};
    f32x4 acc1 = {0.f, 0.f, 0.f, 0.f};
    f32x4 acc2 = {0.f, 0.f, 0.f, 0.f};

#pragma unroll
    for (int pass = 0; pass < 2; pass++) {
      // ---- stage OWN tiles' rows (groups 4w..4w+3, 4w+16..4w+19, w0: 32..35) ----
#pragma unroll
      for (int g = 0; g < 4; g++) {
        const int s = 4 * wid + g;
        const int r = 4 * s + hi;
        gload_lds16(f2tb + rowoff[r] + pass * 256 + ((lo * 16) ^ ((r & 7) << 4)),
                    &halo[s * 1024]);
      }
#pragma unroll
      for (int g = 0; g < 4; g++) {
        const int s = 4 * wid + 16 + g;
        const int r = 4 * s + hi;
        gload_lds16(f2tb + rowoff[r] + pass * 256 + ((lo * 16) ^ ((r & 7) << 4)),
                    &halo[s * 1024]);
      }
      if (wid == 0) {
#pragma unroll
        for (int g = 0; g < 4; g++) {
          const int s = 32 + g;
          const int r = 4 * s + hi;
          gload_lds16(f2tb + rowoff[r] + pass * 256 + ((lo * 16) ^ ((r & 7) << 4)),
                      &halo[s * 1024]);
        }
      }
      asm volatile("s_waitcnt vmcnt(0)" ::: "memory");   // own stages landed
      __builtin_amdgcn_sched_barrier(0);

      {
        const int rr = wid * 16 + lo;
        const int swz = (rr & 7) << 4;
        const char* rp = halo + rr * HROWB;
        short8v a0 = *(const short8v*)(rp + ((hi * 16 + 0) ^ swz));
        short8v a1 = *(const short8v*)(rp + ((hi * 16 + 64) ^ swz));
        short8v a2 = *(const short8v*)(rp + ((hi * 16 + 128) ^ swz));
        short8v a3 = *(const short8v*)(rp + ((hi * 16 + 192) ^ swz));
        acc0 = __builtin_amdgcn_mfma_f32_16x16x32_bf16(a0, bq[pass * 4 + 0], acc0, 0, 0, 0);
        acc0 = __builtin_amdgcn_mfma_f32_16x16x32_bf16(a1, bq[pass * 4 + 1], acc0, 0, 0, 0);
        acc0 = __builtin_amdgcn_mfma_f32_16x16x32_bf16(a2, bq[pass * 4 + 2], acc0, 0, 0, 0);
        acc0 = __builtin_amdgcn_mfma_f32_16x16x32_bf16(a3, bq[pass * 4 + 3], acc0, 0, 0, 0);
      }
      {
        const int rr = (wid + 4) * 16 + lo;
        const int swz = (rr & 7) << 4;
        const char* rp = halo + rr * HROWB;
        short8v a0 = *(const short8v*)(rp + ((hi * 16 + 0) ^ swz));
        short8v a1 = *(const short8v*)(rp + ((hi * 16 + 64) ^ swz));
        short8v a2 = *(const short8v*)(rp + ((hi * 16 + 128) ^ swz));
        short8v a3 = *(const short8v*)(rp + ((hi * 16 + 192) ^ swz));
        acc1 = __builtin_amdgcn_mfma_f32_16x16x32_bf16(a0, bq[pass * 4 + 0], acc1, 0, 0, 0);
        acc1 = __builtin_amdgcn_mfma_f32_16x16x32_bf16(a1, bq[pass * 4 + 1], acc1, 0, 0, 0);
        acc1 = __builtin_amdgcn_mfma_f32_16x16x32_bf16(a2, bq[pass * 4 + 2], acc1, 0, 0, 0);
        acc1 = __builtin_amdgcn_mfma_f32_16x16x32_bf16(a3, bq[pass * 4 + 3], acc1, 0, 0, 0);
      }
      if (wid == 0) {
        const int rr = 8 * 16 + lo;
        const int swz = (rr & 7) << 4;
        const char* rp = halo + rr * HROWB;
        short8v a0 = *(const short8v*)(rp + ((hi * 16 + 0) ^ swz));
        short8v a1 = *(const short8v*)(rp + ((hi * 16 + 64) ^ swz));
        short8v a2 = *(const short8v*)(rp + ((hi * 16 + 128) ^ swz));
        short8v a3 = *(const short8v*)(rp + ((hi * 16 + 192) ^ swz));
        acc2 = __builtin_amdgcn_mfma_f32_16x16x32_bf16(a0, bq[pass * 4 + 0], acc2, 0, 0, 0);
        acc2 = __builtin_amdgcn_mfma_f32_16x16x32_bf16(a1, bq[pass * 4 + 1], acc2, 0, 0, 0);
        acc2 = __builtin_amdgcn_mfma_f32_16x16x32_bf16(a2, bq[pass * 4 + 2], acc2, 0, 0, 0);
        acc2 = __builtin_amdgcn_mfma_f32_16x16x32_bf16(a3, bq[pass * 4 + 3], acc2, 0, 0, 0);
      }
      // ds_reads fully complete (data in VGPRs) before next pass's DMA overwrite
      asm volatile("s_waitcnt lgkmcnt(0)" ::: "memory");
      __builtin_amdgcn_sched_barrier(0);
    }

    // D layout: col = lo, row = hi*4 + j  (each wave writes own dsf rows)
#pragma unroll
    for (int j = 0; j < 4; j++)
      dsf[(wid * 16 + hi * 4 + j) * 16 + lo] = acc0[j];
#pragma unroll
    for (int j = 0; j < 4; j++)
      dsf[((wid + 4) * 16 + hi * 4 + j) * 16 + lo] = acc1[j];
    if (wid == 0) {
#pragma unroll
      for (int j = 0; j < 4; j++)
        dsf[(8 * 16 + hi * 4 + j) * 16 + lo] = acc2[j];
    }
    __syncthreads();                          // dsf ready (cross-wave)

    // bilinear: thread t -> pixel slot t&15, outputs o in [(t>>4)*6, +6)
    // writes ALL 96 k-rows of cbl (zeros for o>=81)
    {
      const int s2 = tid & 15;
      const int g = tid >> 4;
      const int slot2 = b * 16 + s2;
      if (slot2 < npix) {
        const int pi2 = plist[cell * CAP + slot2];
        const float cx = coords[pi2];
        const float cy = coords[HWSZ + pi2];
        const float fxf = floorf(cx), fyf = floorf(cy);
        const float fx = cx - fxf, fy = cy - fyf;
        const int ox = (int)fxf - ci * 4;     // 0..3
        const int oy = (int)fyf - cj * 2;     // 0..1
#pragma unroll
        for (int e = 0; e < 6; e++) {
          const int o = g * 6 + e;
          float cv = 0.f;
          if (o < DD2) {
            const int i = o / DD, j = o - i * DD;   // i=x-offset, j=y-offset
            const int rb = (oy + j) * 13 + ox + i;  // <= 128
            const float d00 = dsf[rb * 16 + s2];
            const float d01 = dsf[(rb + 1) * 16 + s2];
            const float d10 = dsf[(rb + 13) * 16 + s2];
            const float d11 = dsf[(rb + 14) * 16 + s2];
            cv = ((1.f - fy) * ((1.f - fx) * d00 + fx * d01) +
                  fy * ((1.f - fx) * d10 + fx * d11)) * 0.0625f;
          }
          cbl[s2 * CBL_STR + o] = (unsigned short)bf16rne(cv);
        }
      }
    }
    __syncthreads();                          // cbl ready (cross-wave)

    // ---- fused DAP: out[o][px] = W(96x96).cbl ; A = Wf fragment-major ----
    {
      short8v bq2[3];
#pragma unroll
      for (int kt = 0; kt < 3; kt++)
        bq2[kt] = *(const short8v*)&cbl[lo * CBL_STR + kt * 32 + hi * 8];
      const int slot3 = b * 16 + lo;
      const bool v3 = slot3 < npix;
      const int po = v3 ? plist[cell * CAP + slot3] : 0;
#pragma unroll
      for (int mi = 0; mi < 2; mi++) {
        const int m = wid + mi * 4;
        if (m < 6) {
          f32x4 acc = {0.f, 0.f, 0.f, 0.f};
#pragma unroll
          for (int kt = 0; kt < 3; kt++) {
            short8v aw = *(const short8v*)(Wf + ((size_t)(m * 3 + kt) * 64 + lane) * 8);
            acc = __builtin_amdgcn_mfma_f32_16x16x32_bf16(aw, bq2[kt], acc, 0, 0, 0);
          }
          if (v3) {
#pragma unroll
            for (int j = 0; j < 4; j++) {
              const int o = m * 16 + hi * 4 + j;
              if (o < DD2) out[(size_t)o * HWSZ + po] = acc[j];
            }
          }
        }
      }
    }
    if (b + 1 < nb) __syncthreads();          // protect dsf/cbl before next batch
  }
}

extern "C" void kernel_launch(void* const* d_in, const int* in_sizes, int n_in,
                              void* d_out, int out_size, void* d_ws, size_t ws_size,
                              hipStream_t stream) {
  const float* f1     = (const float*)d_in[0];
  const float* f2     = (const float*)d_in[1];
  const float* coords = (const float*)d_in[2];
  const float* w_dap  = (const float*)d_in[3];
  float* out = (float*)d_out;

  // ws: [f2tb 2359296][zpage 512][f1tb 2359296][Wf 18432][cnt 2304][plist 73728]
  char* f2tb  = (char*)d_ws;
  char* zpage = f2tb + (size_t)HWSZ * ROWB;
  char* f1tb  = zpage + 512;
  unsigned short* Wf = (unsigned short*)(f1tb + (size_t)HWSZ * ROWB);
  int* cnt   = (int*)(Wf + 9216);
  int* plist = cnt + NCELL;

  hipMemsetAsync(cnt, 0, NCELL * sizeof(int), stream);

  dim3 tgrid((CC / 64) * (HWSZ / 64), 2);
  transpose_to_bf16<<<tgrid, 256, 0, stream>>>(f1, f2, w_dap, coords, f2tb, f1tb,
                                               zpage, Wf, cnt, plist);

  corr_region<<<dim3(NCELL), 256, 0, stream>>>(f2tb, f1tb, coords, cnt, plist, Wf, out);
}

// Round 24
// 29.672 us; speedup vs baseline: 1.0438x; 1.0120x over previous
//
#include <hip/hip_runtime.h>

#define HH   48
#define WW   96
#define CC   256
#define DD   9
#define DD2  81
#define HWSZ (HH * WW)              // 4608
#define ROWB 512                    // bytes per bf16 channel row (256*2)
#define ZOFF ((unsigned)HWSZ * ROWB) // zero page offset from f2tb base
// pixel cells: 4 wide x 2 tall
#define NCX  24
#define NCY  24
#define NCELL (NCX * NCY)           // 576
#define HROWS 143                   // 11 x 13 halo rows
#define HRP   144                   // padded
#define HROWB 256                   // half-K halo row bytes (128 ch)
#define CAP  32                     // pixel list capacity (Poisson(8))
#define CBL_STR 104                 // cbl row stride in shorts (208 B, 16B-aligned)

typedef __attribute__((ext_vector_type(8))) short short8v;  // 8 bf16 (4 VGPRs)
typedef __attribute__((ext_vector_type(4))) float f32x4;

__device__ __forceinline__ unsigned bf16rne(float f) {      // RNE f32->bf16 bits
  unsigned u = __float_as_uint(f);
  return (u + 0x7FFFu + ((u >> 16) & 1u)) >> 16;
}

__device__ __forceinline__ void gload_lds16(const char* g, char* l) {
  __builtin_amdgcn_global_load_lds(
      (const __attribute__((address_space(1))) char*)g,
      (__attribute__((address_space(3))) char*)l, 16, 0, 0);
}

// ---------------- kernel 1: transposes + W-prep + pixel bucketing ----------------
__global__ __launch_bounds__(256) void transpose_to_bf16(
    const float* __restrict__ f1, const float* __restrict__ f2,
    const float* __restrict__ w_dap, const float* __restrict__ coords,
    char* __restrict__ f2tb, char* __restrict__ f1tb, char* __restrict__ zpage,
    unsigned short* __restrict__ Wf, int* __restrict__ cnt,
    int* __restrict__ plist) {
  __shared__ float tile[64][65];
  const float* src = (blockIdx.y == 0) ? f1 : f2;
  char* dst = (blockIdx.y == 0) ? f1tb : f2tb;

  const int tid = threadIdx.x;
  if (blockIdx.y == 0 && blockIdx.x == 0 && tid < 32) {   // zero the 512 B zero page
    float4 z = {0.f, 0.f, 0.f, 0.f};
    *(float4*)(zpage + tid * 16) = z;
  }
  if (blockIdx.y == 0 && blockIdx.x < 36) {   // W-prep: 9216 shorts over 36 blocks
    int gid = blockIdx.x * 256 + tid;
    int g = gid >> 9;                         // (m,kt) group 0..17
    int idx = gid & 511;
    int ln = idx >> 3, e = idx & 7;
    int m = g / 3, kt = g - m * 3;
    int r = m * 16 + (ln & 15);
    int c = kt * 32 + (ln >> 4) * 8 + e;
    float v = (r < DD2 && c < DD2) ? w_dap[r * DD2 + c] : 0.f;
    Wf[gid] = (unsigned short)bf16rne(v);
  }
  if (blockIdx.y == 1 && blockIdx.x < 18) {   // bucket pixels (cnt pre-zeroed)
    const int p = blockIdx.x * 256 + tid;
    const int ix = (int)coords[p];
    const int iy = (int)coords[HWSZ + p];
    const int cell = (iy >> 1) * NCX + (ix >> 2);
    const int slot = atomicAdd(&cnt[cell], 1);
    if (slot < CAP) plist[cell * CAP + slot] = p;
  }

  const int tiles_p = HWSZ / 64;              // 72
  const int bc = blockIdx.x / tiles_p;        // channel tile 0..3
  const int bp = blockIdx.x % tiles_p;        // pixel tile 0..71
  const int c0 = bc * 64, p0 = bp * 64;

#pragma unroll
  for (int k = 0; k < 16; k++) {
    int idx = k * 256 + tid;
    int cl = idx >> 6, pl = idx & 63;         // coalesced over pixels
    tile[cl][pl] = src[(size_t)(c0 + cl) * HWSZ + p0 + pl];
  }
  __syncthreads();
#pragma unroll
  for (int k = 0; k < 8; k++) {               // pack 2 channels -> 4 B stores
    int idx = k * 256 + tid;
    int pl = idx >> 5, cp = idx & 31;
    unsigned lo = bf16rne(tile[2 * cp][pl]);
    unsigned hi = bf16rne(tile[2 * cp + 1][pl]);
    *(unsigned*)(dst + (size_t)(p0 + pl) * ROWB + (size_t)c0 * 2 + cp * 4) =
        lo | (hi << 16);
  }
}

// ---------------- kernel 2: per-cell halo GEMM, wave-owned staging + COUNTED vmcnt ----------------
// T4 applied per-wave: wait vmcnt(4) -> compute tile w while tile w+4's rows
// still in flight -> vmcnt(0) -> tile w+4 (w0: vmcnt(8)/(4)/(0) for 3 tiles).
// sched_barrier(0) between issue groups pins intrinsic issue order (counting
// relies on in-order vmcnt retirement). Counted-wait safety: remaining <= N
// outstanding are the NEWEST N issued ops = groups after the one we need.
__global__ __launch_bounds__(256, 3) void corr_region(
    const char* __restrict__ f2tb, const char* __restrict__ f1tb,
    const float* __restrict__ coords, const int* __restrict__ cnt,
    const int* __restrict__ plist, const unsigned short* __restrict__ Wf,
    float* __restrict__ out) {
  __shared__ __align__(16) char halo[HRP * HROWB];  // 36864 B
  __shared__ float dsf[HRP * 16];                   // 9216 B
  __shared__ unsigned rowoff[HRP];                  // 576 B
  __shared__ __align__(16) unsigned short cbl[16 * CBL_STR];  // 3328 B

  const int cell = blockIdx.x;
  const int ci = cell % NCX, cj = cell / NCX;
  const int npix0 = cnt[cell];
  const int npix = npix0 < CAP ? npix0 : CAP;
  if (npix == 0) return;

  const int tid = threadIdx.x;
  const int lane = tid & 63, wid = tid >> 6;
  const int hi = lane >> 4, lo = lane & 15;

  const int hx0 = ci * 4 - 4, hy0 = cj * 2 - 4;     // halo origin

  if (tid < HRP) {                            // r -> f2tb byte offset (pad -> zero page)
    unsigned ro = ZOFF;
    if (tid < HROWS) {
      const int hy = (tid * 158) >> 11;       // r/13 (exact for r<143)
      const int hx = tid - hy * 13;
      const int gy = hy0 + hy, gx = hx0 + hx;
      if (gx >= 0 && gx < WW && gy >= 0 && gy < HH)
        ro = (unsigned)(gy * WW + gx) * ROWB;
    }
    rowoff[tid] = ro;
  }
  __syncthreads();                            // rowoff ready (once per block)

  const int nb = (npix + 15) >> 4;
  for (int b = 0; b < nb; ++b) {
    // B fragments: 16 pixel columns (col = lo); invalid slots -> zero page
    const int slot = b * 16 + lo;
    const bool valid = slot < npix;
    const int pi = valid ? plist[cell * CAP + slot] : 0;
    const char* fb = valid ? (f1tb + (size_t)pi * ROWB) : (f2tb + ZOFF);
    short8v bq[8];
#pragma unroll
    for (int kt = 0; kt < 8; kt++)
      bq[kt] = *(const short8v*)(fb + kt * 64 + hi * 16);

    f32x4 acc0 = {0.f, 0.f, 0.f, 0.f};
    f32x4 acc1 = {0.f, 0.f, 0.f, 0.f};
    f32x4 acc2 = {0.f, 0.f, 0.f, 0.f};

#pragma unroll
    for (int pass = 0; pass < 2; pass++) {
      // ---- issue group A: own tile-w rows (s = 4w..4w+3) ----
#pragma unroll
      for (int g = 0; g < 4; g++) {
        const int s = 4 * wid + g;
        const int r = 4 * s + hi;
        gload_lds16(f2tb + rowoff[r] + pass * 256 + ((lo * 16) ^ ((r & 7) << 4)),
                    &halo[s * 1024]);
      }
      __builtin_amdgcn_sched_barrier(0);      // pin A before B
      // ---- issue group B: tile w+4 rows (s = 4w+16..4w+19) ----
#pragma unroll
      for (int g = 0; g < 4; g++) {
        const int s = 4 * wid + 16 + g;
        const int r = 4 * s + hi;
        gload_lds16(f2tb + rowoff[r] + pass * 256 + ((lo * 16) ^ ((r & 7) << 4)),
                    &halo[s * 1024]);
      }
      if (wid == 0) {
        __builtin_amdgcn_sched_barrier(0);    // pin B before C
#pragma unroll
        for (int g = 0; g < 4; g++) {         // group C: tile 8 rows (s = 32..35)
          const int s = 32 + g;
          const int r = 4 * s + hi;
          gload_lds16(f2tb + rowoff[r] + pass * 256 + ((lo * 16) ^ ((r & 7) << 4)),
                      &halo[s * 1024]);
        }
      }

      // ---- counted wait: group A landed (newest 4/8 = B / B+C still fly) ----
      if (wid == 0) asm volatile("s_waitcnt vmcnt(8)" ::: "memory");
      else          asm volatile("s_waitcnt vmcnt(4)" ::: "memory");
      __builtin_amdgcn_sched_barrier(0);

      {                                        // tile w (B-group loads in flight)
        const int rr = wid * 16 + lo;
        const int swz = (rr & 7) << 4;
        const char* rp = halo + rr * HROWB;
        short8v a0 = *(const short8v*)(rp + ((hi * 16 + 0) ^ swz));
        short8v a1 = *(const short8v*)(rp + ((hi * 16 + 64) ^ swz));
        short8v a2 = *(const short8v*)(rp + ((hi * 16 + 128) ^ swz));
        short8v a3 = *(const short8v*)(rp + ((hi * 16 + 192) ^ swz));
        acc0 = __builtin_amdgcn_mfma_f32_16x16x32_bf16(a0, bq[pass * 4 + 0], acc0, 0, 0, 0);
        acc0 = __builtin_amdgcn_mfma_f32_16x16x32_bf16(a1, bq[pass * 4 + 1], acc0, 0, 0, 0);
        acc0 = __builtin_amdgcn_mfma_f32_16x16x32_bf16(a2, bq[pass * 4 + 2], acc0, 0, 0, 0);
        acc0 = __builtin_amdgcn_mfma_f32_16x16x32_bf16(a3, bq[pass * 4 + 3], acc0, 0, 0, 0);
      }

      if (wid == 0) asm volatile("s_waitcnt vmcnt(4)" ::: "memory");
      else          asm volatile("s_waitcnt vmcnt(0)" ::: "memory");
      __builtin_amdgcn_sched_barrier(0);

      {                                        // tile w+4
        const int rr = (wid + 4) * 16 + lo;
        const int swz = (rr & 7) << 4;
        const char* rp = halo + rr * HROWB;
        short8v a0 = *(const short8v*)(rp + ((hi * 16 + 0) ^ swz));
        short8v a1 = *(const short8v*)(rp + ((hi * 16 + 64) ^ swz));
        short8v a2 = *(const short8v*)(rp + ((hi * 16 + 128) ^ swz));
        short8v a3 = *(const short8v*)(rp + ((hi * 16 + 192) ^ swz));
        acc1 = __builtin_amdgcn_mfma_f32_16x16x32_bf16(a0, bq[pass * 4 + 0], acc1, 0, 0, 0);
        acc1 = __builtin_amdgcn_mfma_f32_16x16x32_bf16(a1, bq[pass * 4 + 1], acc1, 0, 0, 0);
        acc1 = __builtin_amdgcn_mfma_f32_16x16x32_bf16(a2, bq[pass * 4 + 2], acc1, 0, 0, 0);
        acc1 = __builtin_amdgcn_mfma_f32_16x16x32_bf16(a3, bq[pass * 4 + 3], acc1, 0, 0, 0);
      }

      if (wid == 0) {
        asm volatile("s_waitcnt vmcnt(0)" ::: "memory");
        __builtin_amdgcn_sched_barrier(0);
        const int rr = 8 * 16 + lo;           // tile 8
        const int swz = (rr & 7) << 4;
        const char* rp = halo + rr * HROWB;
        short8v a0 = *(const short8v*)(rp + ((hi * 16 + 0) ^ swz));
        short8v a1 = *(const short8v*)(rp + ((hi * 16 + 64) ^ swz));
        short8v a2 = *(const short8v*)(rp + ((hi * 16 + 128) ^ swz));
        short8v a3 = *(const short8v*)(rp + ((hi * 16 + 192) ^ swz));
        acc2 = __builtin_amdgcn_mfma_f32_16x16x32_bf16(a0, bq[pass * 4 + 0], acc2, 0, 0, 0);
        acc2 = __builtin_amdgcn_mfma_f32_16x16x32_bf16(a1, bq[pass * 4 + 1], acc2, 0, 0, 0);
        acc2 = __builtin_amdgcn_mfma_f32_16x16x32_bf16(a2, bq[pass * 4 + 2], acc2, 0, 0, 0);
        acc2 = __builtin_amdgcn_mfma_f32_16x16x32_bf16(a3, bq[pass * 4 + 3], acc2, 0, 0, 0);
      }
      // ds_reads fully complete (data in VGPRs) before next pass's DMA overwrite
      asm volatile("s_waitcnt lgkmcnt(0)" ::: "memory");
      __builtin_amdgcn_sched_barrier(0);
    }

    // D layout: col = lo, row = hi*4 + j  (each wave writes own dsf rows)
#pragma unroll
    for (int j = 0; j < 4; j++)
      dsf[(wid * 16 + hi * 4 + j) * 16 + lo] = acc0[j];
#pragma unroll
    for (int j = 0; j < 4; j++)
      dsf[((wid + 4) * 16 + hi * 4 + j) * 16 + lo] = acc1[j];
    if (wid == 0) {
#pragma unroll
      for (int j = 0; j < 4; j++)
        dsf[(8 * 16 + hi * 4 + j) * 16 + lo] = acc2[j];
    }
    __syncthreads();                          // dsf ready (cross-wave)

    // bilinear: thread t -> pixel slot t&15, outputs o in [(t>>4)*6, +6)
    // writes ALL 96 k-rows of cbl (zeros for o>=81)
    {
      const int s2 = tid & 15;
      const int g = tid >> 4;
      const int slot2 = b * 16 + s2;
      if (slot2 < npix) {
        const int pi2 = plist[cell * CAP + slot2];
        const float cx = coords[pi2];
        const float cy = coords[HWSZ + pi2];
        const float fxf = floorf(cx), fyf = floorf(cy);
        const float fx = cx - fxf, fy = cy - fyf;
        const int ox = (int)fxf - ci * 4;     // 0..3
        const int oy = (int)fyf - cj * 2;     // 0..1
#pragma unroll
        for (int e = 0; e < 6; e++) {
          const int o = g * 6 + e;
          float cv = 0.f;
          if (o < DD2) {
            const int i = o / DD, j = o - i * DD;   // i=x-offset, j=y-offset
            const int rb = (oy + j) * 13 + ox + i;  // <= 128
            const float d00 = dsf[rb * 16 + s2];
            const float d01 = dsf[(rb + 1) * 16 + s2];
            const float d10 = dsf[(rb + 13) * 16 + s2];
            const float d11 = dsf[(rb + 14) * 16 + s2];
            cv = ((1.f - fy) * ((1.f - fx) * d00 + fx * d01) +
                  fy * ((1.f - fx) * d10 + fx * d11)) * 0.0625f;
          }
          cbl[s2 * CBL_STR + o] = (unsigned short)bf16rne(cv);
        }
      }
    }
    __syncthreads();                          // cbl ready (cross-wave)

    // ---- fused DAP: out[o][px] = W(96x96).cbl ; A = Wf fragment-major ----
    {
      short8v bq2[3];
#pragma unroll
      for (int kt = 0; kt < 3; kt++)
        bq2[kt] = *(const short8v*)&cbl[lo * CBL_STR + kt * 32 + hi * 8];
      const int slot3 = b * 16 + lo;
      const bool v3 = slot3 < npix;
      const int po = v3 ? plist[cell * CAP + slot3] : 0;
#pragma unroll
      for (int mi = 0; mi < 2; mi++) {
        const int m = wid + mi * 4;
        if (m < 6) {
          f32x4 acc = {0.f, 0.f, 0.f, 0.f};
#pragma unroll
          for (int kt = 0; kt < 3; kt++) {
            short8v aw = *(const short8v*)(Wf + ((size_t)(m * 3 + kt) * 64 + lane) * 8);
            acc = __builtin_amdgcn_mfma_f32_16x16x32_bf16(aw, bq2[kt], acc, 0, 0, 0);
          }
          if (v3) {
#pragma unroll
            for (int j = 0; j < 4; j++) {
              const int o = m * 16 + hi * 4 + j;
              if (o < DD2) out[(size_t)o * HWSZ + po] = acc[j];
            }
          }
        }
      }
    }
    if (b + 1 < nb) __syncthreads();          // protect dsf/cbl before next batch
  }
}

extern "C" void kernel_launch(void* const* d_in, const int* in_sizes, int n_in,
                              void* d_out, int out_size, void* d_ws, size_t ws_size,
                              hipStream_t stream) {
  const float* f1     = (const float*)d_in[0];
  const float* f2     = (const float*)d_in[1];
  const float* coords = (const float*)d_in[2];
  const float* w_dap  = (const float*)d_in[3];
  float* out = (float*)d_out;

  // ws: [f2tb 2359296][zpage 512][f1tb 2359296][Wf 18432][cnt 2304][plist 73728]
  char* f2tb  = (char*)d_ws;
  char* zpage = f2tb + (size_t)HWSZ * ROWB;
  char* f1tb  = zpage + 512;
  unsigned short* Wf = (unsigned short*)(f1tb + (size_t)HWSZ * ROWB);
  int* cnt   = (int*)(Wf + 9216);
  int* plist = cnt + NCELL;

  hipMemsetAsync(cnt, 0, NCELL * sizeof(int), stream);

  dim3 tgrid((CC / 64) * (HWSZ / 64), 2);
  transpose_to_bf16<<<tgrid, 256, 0, stream>>>(f1, f2, w_dap, coords, f2tb, f1tb,
                                               zpage, Wf, cnt, plist);

  corr_region<<<dim3(NCELL), 256, 0, stream>>>(f2tb, f1tb, coords, cnt, plist, Wf, out);
}